// Round 5
// baseline (473.240 us; speedup 1.0000x reference)
//
#include <hip/hip_runtime.h>
#include <math.h>

#define N_NODES 50000
#define E_EDGES 800000
#define D_DIM   128
#define H_HEADS 8
#define C_CH    16
#define HID_DIM 512
#define ED_DIM  32

typedef __attribute__((ext_vector_type(8))) short short8;
typedef __attribute__((ext_vector_type(4))) float f32x4;

__device__ __forceinline__ short f2bf(float f) {
    unsigned u = __float_as_uint(f);
    return (short)((u + 0x7FFFu + ((u >> 16) & 1u)) >> 16);  // RNE
}
__device__ __forceinline__ float bf2f(short s) {
    return __uint_as_float(((unsigned)(unsigned short)s) << 16);
}

// ============================================================
// Kernel R: repack w1/w2/Wl/Wr/We (fp32 [K][N]) into bf16
// B-fragment order for mfma_f32_16x16x32_bf16.
// ============================================================
__global__ __launch_bounds__(64) void repack_kernel(
    const float* __restrict__ w1, const float* __restrict__ w2,
    const float* __restrict__ Wl, const float* __restrict__ Wr,
    const float* __restrict__ We,
    short8* __restrict__ w1p, short8* __restrict__ w2p,
    short8* __restrict__ Wlp, short8* __restrict__ Wrp,
    short8* __restrict__ Wep)
{
    int b = blockIdx.x;
    const float* src; short8* dst; int Nw, nc, rel;
    if (b < 128)      { src = w1; dst = w1p; Nw = 512; nc = 4;  rel = b; }
    else if (b < 256) { src = w2; dst = w2p; Nw = 128; nc = 16; rel = b - 128; }
    else if (b < 288) { src = Wl; dst = Wlp; Nw = 128; nc = 4;  rel = b - 256; }
    else if (b < 320) { src = Wr; dst = Wrp; Nw = 128; nc = 4;  rel = b - 288; }
    else              { src = We; dst = Wep; Nw = 128; nc = 1;  rel = b - 320; }
    int t = rel / nc, c = rel % nc;
    int l = threadIdx.x, quad = l >> 4, col = l & 15;
    short8 r;
    #pragma unroll
    for (int j = 0; j < 8; ++j)
        r[j] = f2bf(src[(size_t)(c * 32 + quad * 8 + j) * Nw + t * 16 + col]);
    dst[(size_t)rel * 64 + l] = r;
}

// ============================================================
// Kernel CNT: per-dst degree count + per-edge rank.
// ============================================================
__global__ __launch_bounds__(256) void count_kernel(
    const int* __restrict__ edge_index, unsigned* __restrict__ cnt,
    unsigned short* __restrict__ rank)
{
    int e = blockIdx.x * 256 + threadIdx.x;   // E % 256 == 0
    int dst = edge_index[E_EDGES + e];
    rank[e] = (unsigned short)atomicAdd(&cnt[dst], 1u);
}

// ============================================================
// Kernel A: MFMA node pipeline. 16 nodes/block, 256 thr (4 waves).
// ============================================================
__global__ __launch_bounds__(256) void node_ffn_mfma(
    const float* __restrict__ h,
    const float* __restrict__ b1, const float* __restrict__ b2,
    const float* __restrict__ ln_g, const float* __restrict__ ln_b,
    const float* __restrict__ bl, const float* __restrict__ br,
    const short8* __restrict__ w1p, const short8* __restrict__ w2p,
    const short8* __restrict__ Wlp, const short8* __restrict__ Wrp,
    float* __restrict__ v_out,
    unsigned short* __restrict__ xl_bf_out, unsigned short* __restrict__ xr_bf_out)
{
    __shared__ short hid_bf[16 * 520];
    __shared__ float v_s[16 * 132];
    __shared__ short v_bf[16 * 136];

    const int tid = threadIdx.x;
    const int w = tid >> 6, lane = tid & 63;
    const int m = lane & 15, quad = lane >> 4;
    const int n0 = blockIdx.x * 16;

    short8 af[4];
    #pragma unroll
    for (int c = 0; c < 4; ++c) {
        const float* hp = h + (size_t)(n0 + m) * 128 + c * 32 + quad * 8;
        float4 p0 = ((const float4*)hp)[0];
        float4 p1 = ((const float4*)hp)[1];
        short8 a;
        a[0] = f2bf(p0.x); a[1] = f2bf(p0.y); a[2] = f2bf(p0.z); a[3] = f2bf(p0.w);
        a[4] = f2bf(p1.x); a[5] = f2bf(p1.y); a[6] = f2bf(p1.z); a[7] = f2bf(p1.w);
        af[c] = a;
    }

    {
        f32x4 acc[8];
        #pragma unroll
        for (int t = 0; t < 8; ++t) acc[t] = (f32x4){0.f, 0.f, 0.f, 0.f};
        #pragma unroll
        for (int t = 0; t < 8; ++t) {
            int tile = w * 8 + t;
            #pragma unroll
            for (int c = 0; c < 4; ++c) {
                short8 bf = w1p[(size_t)(tile * 4 + c) * 64 + lane];
                acc[t] = __builtin_amdgcn_mfma_f32_16x16x32_bf16(af[c], bf, acc[t], 0, 0, 0);
            }
        }
        #pragma unroll
        for (int t = 0; t < 8; ++t) {
            int col = (w * 8 + t) * 16 + m;
            float bias = b1[col];
            #pragma unroll
            for (int r = 0; r < 4; ++r) {
                int row = quad * 4 + r;
                hid_bf[row * 520 + col] = f2bf(fmaxf(acc[t][r] + bias, 0.f));
            }
        }
    }
    __syncthreads();

    {
        f32x4 acc2[2];
        acc2[0] = (f32x4){0.f, 0.f, 0.f, 0.f};
        acc2[1] = (f32x4){0.f, 0.f, 0.f, 0.f};
        #pragma unroll 4
        for (int c = 0; c < 16; ++c) {
            short8 a = *(const short8*)&hid_bf[m * 520 + c * 32 + quad * 8];
            #pragma unroll
            for (int t = 0; t < 2; ++t) {
                short8 bf = w2p[(size_t)((w * 2 + t) * 16 + c) * 64 + lane];
                acc2[t] = __builtin_amdgcn_mfma_f32_16x16x32_bf16(a, bf, acc2[t], 0, 0, 0);
            }
        }
        #pragma unroll
        for (int t = 0; t < 2; ++t) {
            int col = (w * 2 + t) * 16 + m;
            float bias = b2[col];
            #pragma unroll
            for (int r = 0; r < 4; ++r) {
                int row = quad * 4 + r;
                v_s[row * 132 + col] = acc2[t][r] + bias + h[(size_t)(n0 + row) * 128 + col];
            }
        }
    }
    __syncthreads();

    {
        float g0 = ln_g[lane], g1 = ln_g[lane + 64];
        float be0 = ln_b[lane], be1 = ln_b[lane + 64];
        #pragma unroll
        for (int p = 0; p < 4; ++p) {
            int nd = w * 4 + p;
            float x0 = v_s[nd * 132 + lane], x1 = v_s[nd * 132 + lane + 64];
            float s = x0 + x1, ss = x0 * x0 + x1 * x1;
            #pragma unroll
            for (int off = 1; off < 64; off <<= 1) {
                s  += __shfl_xor(s, off);
                ss += __shfl_xor(ss, off);
            }
            float mu = s * (1.f / 128.f);
            float var = ss * (1.f / 128.f) - mu * mu;
            float rs = rsqrtf(var + 1e-5f);
            float y0 = (x0 - mu) * rs * g0 + be0;
            float y1 = (x1 - mu) * rs * g1 + be1;
            v_out[(size_t)(n0 + nd) * 128 + lane]      = y0;
            v_out[(size_t)(n0 + nd) * 128 + lane + 64] = y1;
            v_bf[nd * 136 + lane]      = f2bf(y0);
            v_bf[nd * 136 + lane + 64] = f2bf(y1);
        }
    }
    __syncthreads();

    {
        short8 af3[4];
        #pragma unroll
        for (int c = 0; c < 4; ++c)
            af3[c] = *(const short8*)&v_bf[m * 136 + c * 32 + quad * 8];
        f32x4 accl[2], accr[2];
        #pragma unroll
        for (int t = 0; t < 2; ++t) {
            accl[t] = (f32x4){0.f, 0.f, 0.f, 0.f};
            accr[t] = (f32x4){0.f, 0.f, 0.f, 0.f};
        }
        #pragma unroll
        for (int t = 0; t < 2; ++t) {
            int tile = w * 2 + t;
            #pragma unroll
            for (int c = 0; c < 4; ++c) {
                accl[t] = __builtin_amdgcn_mfma_f32_16x16x32_bf16(
                    af3[c], Wlp[(size_t)(tile * 4 + c) * 64 + lane], accl[t], 0, 0, 0);
                accr[t] = __builtin_amdgcn_mfma_f32_16x16x32_bf16(
                    af3[c], Wrp[(size_t)(tile * 4 + c) * 64 + lane], accr[t], 0, 0, 0);
            }
        }
        #pragma unroll
        for (int t = 0; t < 2; ++t) {
            int col = (w * 2 + t) * 16 + m;
            float bld = bl[col], brd = br[col];
            #pragma unroll
            for (int r = 0; r < 4; ++r) {
                int row = quad * 4 + r;
                xl_bf_out[(size_t)(n0 + row) * 128 + col] = (unsigned short)f2bf(accl[t][r] + bld);
                xr_bf_out[(size_t)(n0 + row) * 128 + col] = (unsigned short)f2bf(accr[t][r] + brd);
            }
        }
    }
}

// ============================================================
// Kernel S1: exclusive scan, vectorized int4 (13 chunks of 4096)
// ============================================================
__global__ __launch_bounds__(1024) void scan_kernel(
    const unsigned* __restrict__ cnt, int* __restrict__ rowstart)
{
    __shared__ int wsum[16];
    __shared__ int s_carry;
    const int t = threadIdx.x, wv = t >> 6, lane = t & 63;
    if (t == 0) s_carry = 0;
    __syncthreads();
    for (int b4 = 0; b4 < N_NODES / 4; b4 += 1024) {
        int i4 = b4 + t;
        int4 v4 = make_int4(0, 0, 0, 0);
        if (i4 < N_NODES / 4) v4 = ((const int4*)cnt)[i4];
        int v = v4.x + v4.y + v4.z + v4.w;
        int s = v;
        #pragma unroll
        for (int off = 1; off < 64; off <<= 1) {
            int nb = __shfl_up(s, off);
            if (lane >= off) s += nb;
        }
        if (lane == 63) wsum[wv] = s;
        __syncthreads();
        int woff = s_carry;
        for (int k = 0; k < wv; ++k) woff += wsum[k];
        int tot = woff + s;
        if (i4 < N_NODES / 4) {
            int e0 = woff + s - v;
            int4 r;
            r.x = e0;
            r.y = e0 + v4.x;
            r.z = r.y + v4.y;
            r.w = r.z + v4.z;
            ((int4*)rowstart)[i4] = r;
        }
        __syncthreads();
        if (t == 1023) s_carry = tot;
    }
}

// ============================================================
// Kernel S2: scatter edge ids + packed (src,dst) into CSR order
// ============================================================
__global__ __launch_bounds__(256) void scatter_kernel(
    const int* __restrict__ edge_index, const unsigned short* __restrict__ rank,
    const int* __restrict__ rowstart, int* __restrict__ eidx,
    unsigned* __restrict__ srcdst)
{
    int e = blockIdx.x * 256 + threadIdx.x;
    if (e >= E_EDGES) return;
    int src = edge_index[e];
    int dst = edge_index[E_EDGES + e];
    int pos = rowstart[dst] + (int)rank[e];
    eidx[pos] = e;
    srcdst[pos] = (unsigned)src | ((unsigned)dst << 16);   // N < 65536
}

// ============================================================
// Kernel B: edge ex via MFMA xe + gathers, CSR order.
// LDS slimmed to the cross-wave xe tile only (17.4 KB -> 8
// blocks/CU, occupancy cap): We fragments read directly from
// global (8 KB, L1/L2-resident; staging it in LDS wasted
// occupancy), meta via broadcast loads; ONE barrier.
// Writes ex = exp(logit) sequentially in CSR order.
// ============================================================
__global__ __launch_bounds__(256) void edge_logits_mfma(
    const int* __restrict__ eidx, const unsigned* __restrict__ srcdst,
    const float* __restrict__ edge_attr,
    const short8* __restrict__ Wep, const float* __restrict__ att,
    const unsigned short* __restrict__ xl_bf, const unsigned short* __restrict__ xr_bf,
    float* __restrict__ exbuf)
{
    __shared__ short xe_s[64 * 136];   // 17.4 KB bf16
    const int tid = threadIdx.x;
    const int w = tid >> 6, lane = tid & 63;
    const int m = lane & 15, quad = lane >> 4;
    const int p0b = blockIdx.x * 64;   // CSR position base

    // A-frag gathered from edge_attr rows of this tile's edges
    // (edge id via direct broadcast-coalesced load; no LDS staging)
    int em = eidx[p0b + w * 16 + m];
    const float* eap = edge_attr + (size_t)em * 32 + quad * 8;
    float4 p0 = ((const float4*)eap)[0];
    float4 p1 = ((const float4*)eap)[1];
    short8 a;
    a[0] = f2bf(p0.x); a[1] = f2bf(p0.y); a[2] = f2bf(p0.z); a[3] = f2bf(p0.w);
    a[4] = f2bf(p1.x); a[5] = f2bf(p1.y); a[6] = f2bf(p1.z); a[7] = f2bf(p1.w);

    // xe = ea @ We : 8 MFMAs per wave, B-frags straight from global (L2-hot)
    f32x4 acc[8];
    #pragma unroll
    for (int t = 0; t < 8; ++t) acc[t] = (f32x4){0.f, 0.f, 0.f, 0.f};
    #pragma unroll
    for (int t = 0; t < 8; ++t)
        acc[t] = __builtin_amdgcn_mfma_f32_16x16x32_bf16(a, Wep[t * 64 + lane], acc[t], 0, 0, 0);

    #pragma unroll
    for (int t = 0; t < 8; ++t) {
        #pragma unroll
        for (int r = 0; r < 4; ++r)
            xe_s[(w * 16 + quad * 4 + r) * 136 + t * 16 + m] = f2bf(acc[t][r]);
    }
    __syncthreads();

    // per-edge phase: 4 edges/pass per wave; lane = g*16 + s
    const int g = quad;
    const int s = m;
    const int d0 = s * 8;
    float4 at0 = ((const float4*)(att + d0))[0];
    float4 at1 = ((const float4*)(att + d0))[1];

    #pragma unroll
    for (int p = 0; p < 4; ++p) {
        int el = p * 16 + w * 4 + g;
        unsigned sd = srcdst[p0b + el];          // broadcast per 16 lanes, L1-hot
        int src = (int)(sd & 0xffffu);
        int dst = (int)(sd >> 16);
        short8 xl8 = *(const short8*)&xl_bf[(size_t)src * 128 + d0];
        short8 xr8 = *(const short8*)&xr_bf[(size_t)dst * 128 + d0];
        short8 xe8 = *(const short8*)&xe_s[el * 136 + d0];

        float atv[8] = { at0.x, at0.y, at0.z, at0.w, at1.x, at1.y, at1.z, at1.w };
        float pq = 0.f;
        #pragma unroll
        for (int dd = 0; dd < 8; ++dd) {
            float x = bf2f(xl8[dd]) + bf2f(xr8[dd]) + bf2f(xe8[dd]);
            x = (x > 0.f) ? x : 0.2f * x;
            pq += x * atv[dd];
        }
        pq += __shfl_xor(pq, 1);
        if ((s & 1) == 0)
            exbuf[(size_t)(p0b + el) * 8 + (s >> 1)] = expf(pq);
    }
}

// ============================================================
// Kernel C: per-node aggregation, ONE pass:
//   U = sum ex*xl, den = sum ex accumulated together; then
//   out = LN(U/den + bias + v); then alpha sweep writes
//   alpha[e][h] = ex*inv (sequential ex re-read, scatter write).
// ============================================================
__global__ __launch_bounds__(256) void node_aggregate_kernel(
    const int* __restrict__ eidx, const int* __restrict__ rowstart,
    const unsigned* __restrict__ cnt, const unsigned* __restrict__ srcdst,
    const float* __restrict__ exbuf,
    const unsigned short* __restrict__ xl_bf, const float* __restrict__ v,
    const float* __restrict__ bias_out,
    const float* __restrict__ ln_g, const float* __restrict__ ln_b,
    float* __restrict__ alpha_out, float* __restrict__ out)
{
    const int wv = threadIdx.x >> 6, lane = threadIdx.x & 63;
    const int n = blockIdx.x * 4 + wv;
    if (n >= N_NODES) return;
    const int start = rowstart[n];
    const int num = (int)cnt[n];

    // single pass: 4 edges in flight; lane = g*16 + s, channels s*8..s*8+7
    const int g = lane >> 4, s = lane & 15;
    const int h3 = s >> 1;
    float acc[8] = {0.f, 0.f, 0.f, 0.f, 0.f, 0.f, 0.f, 0.f};
    float den = 0.f;
    for (int i = 0; i < num; i += 4) {
        int ii = i + g;
        if (ii < num) {
            int pos = start + ii;
            int src = (int)(srcdst[pos] & 0xffffu);
            float ex = exbuf[(size_t)pos * 8 + h3];          // sequential, L2-warm
            if ((s & 1) == 0) den += ex;
            short8 q = *(const short8*)&xl_bf[(size_t)src * 128 + s * 8];
            acc[0] += bf2f(q[0]) * ex; acc[1] += bf2f(q[1]) * ex;
            acc[2] += bf2f(q[2]) * ex; acc[3] += bf2f(q[3]) * ex;
            acc[4] += bf2f(q[4]) * ex; acc[5] += bf2f(q[5]) * ex;
            acc[6] += bf2f(q[6]) * ex; acc[7] += bf2f(q[7]) * ex;
        }
    }
    #pragma unroll
    for (int k = 0; k < 8; ++k) {
        acc[k] += __shfl_xor(acc[k], 16);
        acc[k] += __shfl_xor(acc[k], 32);
    }
    den += __shfl_xor(den, 16);
    den += __shfl_xor(den, 32);                 // even-s lanes hold den[h]
    float den_h = __shfl(den, 2 * h3);          // broadcast den for this lane's head
    float inv = (num > 0) ? (1.f / den_h) : 0.f;

    // epilogue: LN(U*inv + bias_out + v); lane s holds channels s*8..s*8+7
    const float* vp = v + (size_t)n * 128 + s * 8;
    float4 v0 = ((const float4*)vp)[0], v1 = ((const float4*)vp)[1];
    float4 b0 = ((const float4*)(bias_out + s * 8))[0];
    float4 b1 = ((const float4*)(bias_out + s * 8))[1];
    float x[8];
    x[0] = acc[0] * inv + b0.x + v0.x; x[1] = acc[1] * inv + b0.y + v0.y;
    x[2] = acc[2] * inv + b0.z + v0.z; x[3] = acc[3] * inv + b0.w + v0.w;
    x[4] = acc[4] * inv + b1.x + v1.x; x[5] = acc[5] * inv + b1.y + v1.y;
    x[6] = acc[6] * inv + b1.z + v1.z; x[7] = acc[7] * inv + b1.w + v1.w;
    float sm = 0.f, ssm = 0.f;
    #pragma unroll
    for (int k = 0; k < 8; ++k) { sm += x[k]; ssm += x[k] * x[k]; }
    #pragma unroll
    for (int off = 1; off < 16; off <<= 1) {
        sm  += __shfl_xor(sm, off);
        ssm += __shfl_xor(ssm, off);
    }
    float mu = sm * (1.f / 128.f);
    float var = ssm * (1.f / 128.f) - mu * mu;
    float rs = rsqrtf(var + 1e-5f);
    if (g == 0) {
        float4 g0 = ((const float4*)(ln_g + s * 8))[0];
        float4 g1 = ((const float4*)(ln_g + s * 8))[1];
        float4 be0 = ((const float4*)(ln_b + s * 8))[0];
        float4 be1 = ((const float4*)(ln_b + s * 8))[1];
        float4 o0, o1;
        o0.x = (x[0] - mu) * rs * g0.x + be0.x;
        o0.y = (x[1] - mu) * rs * g0.y + be0.y;
        o0.z = (x[2] - mu) * rs * g0.z + be0.z;
        o0.w = (x[3] - mu) * rs * g0.w + be0.w;
        o1.x = (x[4] - mu) * rs * g1.x + be1.x;
        o1.y = (x[5] - mu) * rs * g1.y + be1.y;
        o1.z = (x[6] - mu) * rs * g1.z + be1.z;
        o1.w = (x[7] - mu) * rs * g1.w + be1.w;
        float4* op = (float4*)(out + (size_t)n * 128 + s * 8);
        op[0] = o0; op[1] = o1;
    }

    // alpha sweep: alpha[e][h] = ex * inv (scatter, 32B-coalesced)
    if (num > 0) {
        const int h7 = lane & 7, j8 = lane >> 3;   // 8 edges in flight
        float invh = __shfl(inv, 2 * h7);
        for (int i = j8; i < num; i += 8) {
            int pos = start + i;
            float ex = exbuf[(size_t)pos * 8 + h7];
            int e = eidx[pos];                      // same addr per 8 lanes
            alpha_out[(size_t)e * 8 + h7] = ex * invh;
        }
    }
}

// ============================================================
extern "C" void kernel_launch(void* const* d_in, const int* in_sizes, int n_in,
                              void* d_out, int out_size, void* d_ws, size_t ws_size,
                              hipStream_t stream)
{
    const float* h        = (const float*)d_in[0];
    const int*   edge_idx = (const int*)  d_in[1];
    const float* edge_attr= (const float*)d_in[2];
    const float* w1       = (const float*)d_in[3];
    const float* b1       = (const float*)d_in[4];
    const float* w2       = (const float*)d_in[5];
    const float* b2       = (const float*)d_in[6];
    const float* ln_g     = (const float*)d_in[7];
    const float* ln_b     = (const float*)d_in[8];
    const float* Wl       = (const float*)d_in[9];
    const float* bl       = (const float*)d_in[10];
    const float* Wr       = (const float*)d_in[11];
    const float* br       = (const float*)d_in[12];
    const float* We       = (const float*)d_in[13];
    const float* att      = (const float*)d_in[14];
    const float* bias_out = (const float*)d_in[15];

    float* out   = (float*)d_out;                       // [N,128]
    float* alpha = out + (size_t)N_NODES * 128;         // [E,8] final alpha

    short8* w1p = (short8*)alpha;                       // packed weights live in
    short8* w2p = w1p + 128 * 64;                       // alpha region, consumed by
    short8* Wlp = w2p + 128 * 64;                       // node_ffn; alpha written last
    short8* Wrp = Wlp + 32 * 64;

    float*          v        = (float*)d_ws;                               // [N,128] f32
    unsigned short* xl_bf    = (unsigned short*)(v + (size_t)N_NODES*128); // [N,128] bf16
    unsigned short* xr_bf    = xl_bf + (size_t)N_NODES * 128;              // [N,128] bf16
    float*          exbuf    = (float*)(xr_bf + (size_t)N_NODES * 128);    // [E,8] f32 (ex)
    unsigned*       cnt      = (unsigned*)(exbuf + (size_t)E_EDGES * 8);   // [N]
    int*            rowstart = (int*)(cnt + N_NODES);                      // [N]
    unsigned short* rank     = (unsigned short*)(rowstart + N_NODES);      // [E]
    short8*         Wep      = (short8*)(rank + E_EDGES);                  // [512] 8 KB
    int*            eidx     = (int*)(Wep + 512);                          // [E]
    unsigned*       srcdst   = (unsigned*)(eidx + E_EDGES);                // [E]

    hipMemsetAsync(cnt, 0, (size_t)N_NODES * sizeof(unsigned), stream);

    repack_kernel<<<328, 64, 0, stream>>>(w1, w2, Wl, Wr, We,
                                          w1p, w2p, Wlp, Wrp, Wep);
    count_kernel<<<E_EDGES / 256, 256, 0, stream>>>(edge_idx, cnt, rank);
    node_ffn_mfma<<<N_NODES / 16, 256, 0, stream>>>(
        h, b1, b2, ln_g, ln_b, bl, br, w1p, w2p, Wlp, Wrp, v, xl_bf, xr_bf);
    scan_kernel<<<1, 1024, 0, stream>>>(cnt, rowstart);
    scatter_kernel<<<(E_EDGES + 255) / 256, 256, 0, stream>>>(
        edge_idx, rank, rowstart, eidx, srcdst);
    edge_logits_mfma<<<E_EDGES / 64, 256, 0, stream>>>(
        eidx, srcdst, edge_attr, Wep, att, xl_bf, xr_bf, exbuf);
    node_aggregate_kernel<<<(N_NODES + 3) / 4, 256, 0, stream>>>(
        eidx, rowstart, cnt, srcdst, exbuf, xl_bf, v, bias_out, ln_g, ln_b, alpha, out);
}

// Round 6
// 436.182 us; speedup vs baseline: 1.0850x; 1.0850x over previous
//
#include <hip/hip_runtime.h>
#include <math.h>

#define N_NODES 50000
#define E_EDGES 800000
#define D_DIM   128
#define H_HEADS 8
#define C_CH    16
#define HID_DIM 512
#define ED_DIM  32

typedef __attribute__((ext_vector_type(8))) short short8;
typedef __attribute__((ext_vector_type(4))) float f32x4;

__device__ __forceinline__ short f2bf(float f) {
    unsigned u = __float_as_uint(f);
    return (short)((u + 0x7FFFu + ((u >> 16) & 1u)) >> 16);  // RNE
}
__device__ __forceinline__ float bf2f(short s) {
    return __uint_as_float(((unsigned)(unsigned short)s) << 16);
}

// ============================================================
// Kernel R: repack w1/w2/Wl/Wr/We (fp32 [K][N]) into bf16
// B-fragment order for mfma_f32_16x16x32_bf16.
// ============================================================
__global__ __launch_bounds__(64) void repack_kernel(
    const float* __restrict__ w1, const float* __restrict__ w2,
    const float* __restrict__ Wl, const float* __restrict__ Wr,
    const float* __restrict__ We,
    short8* __restrict__ w1p, short8* __restrict__ w2p,
    short8* __restrict__ Wlp, short8* __restrict__ Wrp,
    short8* __restrict__ Wep)
{
    int b = blockIdx.x;
    const float* src; short8* dst; int Nw, nc, rel;
    if (b < 128)      { src = w1; dst = w1p; Nw = 512; nc = 4;  rel = b; }
    else if (b < 256) { src = w2; dst = w2p; Nw = 128; nc = 16; rel = b - 128; }
    else if (b < 288) { src = Wl; dst = Wlp; Nw = 128; nc = 4;  rel = b - 256; }
    else if (b < 320) { src = Wr; dst = Wrp; Nw = 128; nc = 4;  rel = b - 288; }
    else              { src = We; dst = Wep; Nw = 128; nc = 1;  rel = b - 320; }
    int t = rel / nc, c = rel % nc;
    int l = threadIdx.x, quad = l >> 4, col = l & 15;
    short8 r;
    #pragma unroll
    for (int j = 0; j < 8; ++j)
        r[j] = f2bf(src[(size_t)(c * 32 + quad * 8 + j) * Nw + t * 16 + col]);
    dst[(size_t)rel * 64 + l] = r;
}

// ============================================================
// Kernel CNT: per-dst degree count + per-edge rank.
// ============================================================
__global__ __launch_bounds__(256) void count_kernel(
    const int* __restrict__ edge_index, unsigned* __restrict__ cnt,
    unsigned short* __restrict__ rank)
{
    int e = blockIdx.x * 256 + threadIdx.x;   // E % 256 == 0
    int dst = edge_index[E_EDGES + e];
    rank[e] = (unsigned short)atomicAdd(&cnt[dst], 1u);
}

// ============================================================
// Kernel A: MFMA node pipeline. 16 nodes/block, 256 thr (4 waves).
// ============================================================
__global__ __launch_bounds__(256) void node_ffn_mfma(
    const float* __restrict__ h,
    const float* __restrict__ b1, const float* __restrict__ b2,
    const float* __restrict__ ln_g, const float* __restrict__ ln_b,
    const float* __restrict__ bl, const float* __restrict__ br,
    const short8* __restrict__ w1p, const short8* __restrict__ w2p,
    const short8* __restrict__ Wlp, const short8* __restrict__ Wrp,
    float* __restrict__ v_out,
    unsigned short* __restrict__ xl_bf_out, unsigned short* __restrict__ xr_bf_out)
{
    __shared__ short hid_bf[16 * 520];
    __shared__ float v_s[16 * 132];
    __shared__ short v_bf[16 * 136];

    const int tid = threadIdx.x;
    const int w = tid >> 6, lane = tid & 63;
    const int m = lane & 15, quad = lane >> 4;
    const int n0 = blockIdx.x * 16;

    short8 af[4];
    #pragma unroll
    for (int c = 0; c < 4; ++c) {
        const float* hp = h + (size_t)(n0 + m) * 128 + c * 32 + quad * 8;
        float4 p0 = ((const float4*)hp)[0];
        float4 p1 = ((const float4*)hp)[1];
        short8 a;
        a[0] = f2bf(p0.x); a[1] = f2bf(p0.y); a[2] = f2bf(p0.z); a[3] = f2bf(p0.w);
        a[4] = f2bf(p1.x); a[5] = f2bf(p1.y); a[6] = f2bf(p1.z); a[7] = f2bf(p1.w);
        af[c] = a;
    }

    {
        f32x4 acc[8];
        #pragma unroll
        for (int t = 0; t < 8; ++t) acc[t] = (f32x4){0.f, 0.f, 0.f, 0.f};
        #pragma unroll
        for (int t = 0; t < 8; ++t) {
            int tile = w * 8 + t;
            #pragma unroll
            for (int c = 0; c < 4; ++c) {
                short8 bf = w1p[(size_t)(tile * 4 + c) * 64 + lane];
                acc[t] = __builtin_amdgcn_mfma_f32_16x16x32_bf16(af[c], bf, acc[t], 0, 0, 0);
            }
        }
        #pragma unroll
        for (int t = 0; t < 8; ++t) {
            int col = (w * 8 + t) * 16 + m;
            float bias = b1[col];
            #pragma unroll
            for (int r = 0; r < 4; ++r) {
                int row = quad * 4 + r;
                hid_bf[row * 520 + col] = f2bf(fmaxf(acc[t][r] + bias, 0.f));
            }
        }
    }
    __syncthreads();

    {
        f32x4 acc2[2];
        acc2[0] = (f32x4){0.f, 0.f, 0.f, 0.f};
        acc2[1] = (f32x4){0.f, 0.f, 0.f, 0.f};
        #pragma unroll 4
        for (int c = 0; c < 16; ++c) {
            short8 a = *(const short8*)&hid_bf[m * 520 + c * 32 + quad * 8];
            #pragma unroll
            for (int t = 0; t < 2; ++t) {
                short8 bf = w2p[(size_t)((w * 2 + t) * 16 + c) * 64 + lane];
                acc2[t] = __builtin_amdgcn_mfma_f32_16x16x32_bf16(a, bf, acc2[t], 0, 0, 0);
            }
        }
        #pragma unroll
        for (int t = 0; t < 2; ++t) {
            int col = (w * 2 + t) * 16 + m;
            float bias = b2[col];
            #pragma unroll
            for (int r = 0; r < 4; ++r) {
                int row = quad * 4 + r;
                v_s[row * 132 + col] = acc2[t][r] + bias + h[(size_t)(n0 + row) * 128 + col];
            }
        }
    }
    __syncthreads();

    {
        float g0 = ln_g[lane], g1 = ln_g[lane + 64];
        float be0 = ln_b[lane], be1 = ln_b[lane + 64];
        #pragma unroll
        for (int p = 0; p < 4; ++p) {
            int nd = w * 4 + p;
            float x0 = v_s[nd * 132 + lane], x1 = v_s[nd * 132 + lane + 64];
            float s = x0 + x1, ss = x0 * x0 + x1 * x1;
            #pragma unroll
            for (int off = 1; off < 64; off <<= 1) {
                s  += __shfl_xor(s, off);
                ss += __shfl_xor(ss, off);
            }
            float mu = s * (1.f / 128.f);
            float var = ss * (1.f / 128.f) - mu * mu;
            float rs = rsqrtf(var + 1e-5f);
            float y0 = (x0 - mu) * rs * g0 + be0;
            float y1 = (x1 - mu) * rs * g1 + be1;
            v_out[(size_t)(n0 + nd) * 128 + lane]      = y0;
            v_out[(size_t)(n0 + nd) * 128 + lane + 64] = y1;
            v_bf[nd * 136 + lane]      = f2bf(y0);
            v_bf[nd * 136 + lane + 64] = f2bf(y1);
        }
    }
    __syncthreads();

    {
        short8 af3[4];
        #pragma unroll
        for (int c = 0; c < 4; ++c)
            af3[c] = *(const short8*)&v_bf[m * 136 + c * 32 + quad * 8];
        f32x4 accl[2], accr[2];
        #pragma unroll
        for (int t = 0; t < 2; ++t) {
            accl[t] = (f32x4){0.f, 0.f, 0.f, 0.f};
            accr[t] = (f32x4){0.f, 0.f, 0.f, 0.f};
        }
        #pragma unroll
        for (int t = 0; t < 2; ++t) {
            int tile = w * 2 + t;
            #pragma unroll
            for (int c = 0; c < 4; ++c) {
                accl[t] = __builtin_amdgcn_mfma_f32_16x16x32_bf16(
                    af3[c], Wlp[(size_t)(tile * 4 + c) * 64 + lane], accl[t], 0, 0, 0);
                accr[t] = __builtin_amdgcn_mfma_f32_16x16x32_bf16(
                    af3[c], Wrp[(size_t)(tile * 4 + c) * 64 + lane], accr[t], 0, 0, 0);
            }
        }
        #pragma unroll
        for (int t = 0; t < 2; ++t) {
            int col = (w * 2 + t) * 16 + m;
            float bld = bl[col], brd = br[col];
            #pragma unroll
            for (int r = 0; r < 4; ++r) {
                int row = quad * 4 + r;
                xl_bf_out[(size_t)(n0 + row) * 128 + col] = (unsigned short)f2bf(accl[t][r] + bld);
                xr_bf_out[(size_t)(n0 + row) * 128 + col] = (unsigned short)f2bf(accr[t][r] + brd);
            }
        }
    }
}

// ============================================================
// Kernel S1: exclusive scan, single pass: each thread owns 13
// int4 chunks (52 values, all loads in flight at once), one
// wave-scan + one barrier, then per-thread prefix writeback.
// Replaces the 13-round barrier-chained loop (latency chain).
// ============================================================
__global__ __launch_bounds__(1024) void scan_kernel(
    const unsigned* __restrict__ cnt, int* __restrict__ rowstart)
{
    __shared__ int wsum[16];
    const int t = threadIdx.x, wv = t >> 6, lane = t & 63;
    const int base4 = t * 13;
    int4 v[13];
    int lsum = 0;
    #pragma unroll
    for (int k = 0; k < 13; ++k) {
        int i4 = base4 + k;
        int4 x = make_int4(0, 0, 0, 0);
        if (i4 < N_NODES / 4) x = ((const int4*)cnt)[i4];
        v[k] = x;
        lsum += x.x + x.y + x.z + x.w;
    }
    int s = lsum;
    #pragma unroll
    for (int off = 1; off < 64; off <<= 1) {
        int nb = __shfl_up(s, off);
        if (lane >= off) s += nb;
    }
    if (lane == 63) wsum[wv] = s;
    __syncthreads();
    int woff = 0;
    for (int k = 0; k < wv; ++k) woff += wsum[k];
    int run = woff + s - lsum;          // exclusive prefix for this thread
    #pragma unroll
    for (int k = 0; k < 13; ++k) {
        int i4 = base4 + k;
        if (i4 < N_NODES / 4) {
            int4 r;
            r.x = run; run += v[k].x;
            r.y = run; run += v[k].y;
            r.z = run; run += v[k].z;
            r.w = run; run += v[k].w;
            ((int4*)rowstart)[i4] = r;
        }
    }
}

// ============================================================
// Kernel S2: scatter edge ids + packed (src,dst) into CSR order
// ============================================================
__global__ __launch_bounds__(256) void scatter_kernel(
    const int* __restrict__ edge_index, const unsigned short* __restrict__ rank,
    const int* __restrict__ rowstart, int* __restrict__ eidx,
    unsigned* __restrict__ srcdst)
{
    int e = blockIdx.x * 256 + threadIdx.x;
    if (e >= E_EDGES) return;
    int src = edge_index[e];
    int dst = edge_index[E_EDGES + e];
    int pos = rowstart[dst] + (int)rank[e];
    eidx[pos] = e;
    srcdst[pos] = (unsigned)src | ((unsigned)dst << 16);   // N < 65536
}

// ============================================================
// Kernel B: edge ex via MFMA xe + gathers, CSR order (R4 form:
// We/meta staged in LDS — MFMA operands on the lgkmcnt path).
// Writes ex = exp(logit) sequentially in CSR order.
// ============================================================
__global__ __launch_bounds__(256) void edge_logits_mfma(
    const int* __restrict__ eidx, const unsigned* __restrict__ srcdst,
    const float* __restrict__ edge_attr,
    const short8* __restrict__ Wep, const float* __restrict__ att,
    const unsigned short* __restrict__ xl_bf, const unsigned short* __restrict__ xr_bf,
    float* __restrict__ exbuf)
{
    __shared__ short8 We_f[512];       // 8 KB, B-frag order
    __shared__ short xe_s[64 * 136];   // 17 KB bf16
    __shared__ int e_s[64];
    __shared__ unsigned sd_s[64];
    const int tid = threadIdx.x;
    const int w = tid >> 6, lane = tid & 63;
    const int m = lane & 15, quad = lane >> 4;
    const int p0b = blockIdx.x * 64;   // CSR position base

    We_f[tid]       = Wep[tid];
    We_f[tid + 256] = Wep[tid + 256];
    if (tid < 64) {
        int pos = p0b + tid;
        e_s[tid]  = eidx[pos];
        sd_s[tid] = srcdst[pos];
    }
    __syncthreads();

    // A-frag gathered from edge_attr rows of this tile's edges
    const float* eap = edge_attr + (size_t)e_s[w * 16 + m] * 32 + quad * 8;
    float4 p0 = ((const float4*)eap)[0];
    float4 p1 = ((const float4*)eap)[1];
    short8 a;
    a[0] = f2bf(p0.x); a[1] = f2bf(p0.y); a[2] = f2bf(p0.z); a[3] = f2bf(p0.w);
    a[4] = f2bf(p1.x); a[5] = f2bf(p1.y); a[6] = f2bf(p1.z); a[7] = f2bf(p1.w);

    // xe = ea @ We : 8 MFMAs per wave
    f32x4 acc[8];
    #pragma unroll
    for (int t = 0; t < 8; ++t) acc[t] = (f32x4){0.f, 0.f, 0.f, 0.f};
    #pragma unroll
    for (int t = 0; t < 8; ++t)
        acc[t] = __builtin_amdgcn_mfma_f32_16x16x32_bf16(a, We_f[t * 64 + lane], acc[t], 0, 0, 0);

    #pragma unroll
    for (int t = 0; t < 8; ++t) {
        #pragma unroll
        for (int r = 0; r < 4; ++r)
            xe_s[(w * 16 + quad * 4 + r) * 136 + t * 16 + m] = f2bf(acc[t][r]);
    }
    __syncthreads();

    // per-edge phase: 4 edges/pass per wave; lane = g*16 + s
    const int g = quad;
    const int s = m;
    const int d0 = s * 8;
    float4 at0 = ((const float4*)(att + d0))[0];
    float4 at1 = ((const float4*)(att + d0))[1];

    #pragma unroll
    for (int p = 0; p < 4; ++p) {
        int el = p * 16 + w * 4 + g;
        unsigned sd = sd_s[el];
        int src = (int)(sd & 0xffffu);
        int dst = (int)(sd >> 16);
        short8 xl8 = *(const short8*)&xl_bf[(size_t)src * 128 + d0];
        short8 xr8 = *(const short8*)&xr_bf[(size_t)dst * 128 + d0];
        short8 xe8 = *(const short8*)&xe_s[el * 136 + d0];

        float atv[8] = { at0.x, at0.y, at0.z, at0.w, at1.x, at1.y, at1.z, at1.w };
        float pq = 0.f;
        #pragma unroll
        for (int dd = 0; dd < 8; ++dd) {
            float x = bf2f(xl8[dd]) + bf2f(xr8[dd]) + bf2f(xe8[dd]);
            x = (x > 0.f) ? x : 0.2f * x;
            pq += x * atv[dd];
        }
        pq += __shfl_xor(pq, 1);
        if ((s & 1) == 0)
            exbuf[(size_t)(p0b + el) * 8 + (s >> 1)] = expf(pq);
    }
}

// ============================================================
// Kernel C: per-node aggregation, ONE pass with 8 edges in
// flight (guard-free main loop -> loads freely hoisted):
//   U = sum ex*xl, den = sum ex; out = LN(U/den + bias + v);
//   alpha sweep writes alpha[e][h] = ex*inv.
// ============================================================
__global__ __launch_bounds__(256) void node_aggregate_kernel(
    const int* __restrict__ eidx, const int* __restrict__ rowstart,
    const unsigned* __restrict__ cnt, const unsigned* __restrict__ srcdst,
    const float* __restrict__ exbuf,
    const unsigned short* __restrict__ xl_bf, const float* __restrict__ v,
    const float* __restrict__ bias_out,
    const float* __restrict__ ln_g, const float* __restrict__ ln_b,
    float* __restrict__ alpha_out, float* __restrict__ out)
{
    const int wv = threadIdx.x >> 6, lane = threadIdx.x & 63;
    const int n = blockIdx.x * 4 + wv;
    if (n >= N_NODES) return;
    const int start = rowstart[n];
    const int num = (int)cnt[n];

    // lane = g*16 + s, channels s*8..s*8+7, 4 edge slots (g)
    const int g = lane >> 4, s = lane & 15;
    const int h3 = s >> 1;
    float acc[8] = {0.f, 0.f, 0.f, 0.f, 0.f, 0.f, 0.f, 0.f};
    float den = 0.f;

    int i = 0;
    // main loop: 8 edges per iteration, no divergence (i+7 < num)
    for (; i + 8 <= num; i += 8) {
        int pos0 = start + i + g;
        int pos1 = pos0 + 4;
        unsigned sda = srcdst[pos0];
        unsigned sdb = srcdst[pos1];
        float exa = exbuf[(size_t)pos0 * 8 + h3];
        float exb = exbuf[(size_t)pos1 * 8 + h3];
        short8 qa = *(const short8*)&xl_bf[(size_t)(sda & 0xffffu) * 128 + s * 8];
        short8 qb = *(const short8*)&xl_bf[(size_t)(sdb & 0xffffu) * 128 + s * 8];
        if ((s & 1) == 0) den += exa + exb;
        #pragma unroll
        for (int k = 0; k < 8; ++k) {
            acc[k] += bf2f(qa[k]) * exa;
            acc[k] += bf2f(qb[k]) * exb;
        }
    }
    // tail: guarded, 4 edges per iteration
    for (; i < num; i += 4) {
        int ii = i + g;
        if (ii < num) {
            int pos = start + ii;
            int src = (int)(srcdst[pos] & 0xffffu);
            float ex = exbuf[(size_t)pos * 8 + h3];
            if ((s & 1) == 0) den += ex;
            short8 q = *(const short8*)&xl_bf[(size_t)src * 128 + s * 8];
            #pragma unroll
            for (int k = 0; k < 8; ++k) acc[k] += bf2f(q[k]) * ex;
        }
    }
    #pragma unroll
    for (int k = 0; k < 8; ++k) {
        acc[k] += __shfl_xor(acc[k], 16);
        acc[k] += __shfl_xor(acc[k], 32);
    }
    den += __shfl_xor(den, 16);
    den += __shfl_xor(den, 32);                 // even-s lanes hold den[h]
    float den_h = __shfl(den, 2 * h3);          // broadcast den for this lane's head
    float inv = (num > 0) ? (1.f / den_h) : 0.f;

    // epilogue: LN(U*inv + bias_out + v); lane s holds channels s*8..s*8+7
    const float* vp = v + (size_t)n * 128 + s * 8;
    float4 v0 = ((const float4*)vp)[0], v1 = ((const float4*)vp)[1];
    float4 b0 = ((const float4*)(bias_out + s * 8))[0];
    float4 b1 = ((const float4*)(bias_out + s * 8))[1];
    float x[8];
    x[0] = acc[0] * inv + b0.x + v0.x; x[1] = acc[1] * inv + b0.y + v0.y;
    x[2] = acc[2] * inv + b0.z + v0.z; x[3] = acc[3] * inv + b0.w + v0.w;
    x[4] = acc[4] * inv + b1.x + v1.x; x[5] = acc[5] * inv + b1.y + v1.y;
    x[6] = acc[6] * inv + b1.z + v1.z; x[7] = acc[7] * inv + b1.w + v1.w;
    float sm = 0.f, ssm = 0.f;
    #pragma unroll
    for (int k = 0; k < 8; ++k) { sm += x[k]; ssm += x[k] * x[k]; }
    #pragma unroll
    for (int off = 1; off < 16; off <<= 1) {
        sm  += __shfl_xor(sm, off);
        ssm += __shfl_xor(ssm, off);
    }
    float mu = sm * (1.f / 128.f);
    float var = ssm * (1.f / 128.f) - mu * mu;
    float rs = rsqrtf(var + 1e-5f);
    if (g == 0) {
        float4 g0 = ((const float4*)(ln_g + s * 8))[0];
        float4 g1 = ((const float4*)(ln_g + s * 8))[1];
        float4 be0 = ((const float4*)(ln_b + s * 8))[0];
        float4 be1 = ((const float4*)(ln_b + s * 8))[1];
        float4 o0, o1;
        o0.x = (x[0] - mu) * rs * g0.x + be0.x;
        o0.y = (x[1] - mu) * rs * g0.y + be0.y;
        o0.z = (x[2] - mu) * rs * g0.z + be0.z;
        o0.w = (x[3] - mu) * rs * g0.w + be0.w;
        o1.x = (x[4] - mu) * rs * g1.x + be1.x;
        o1.y = (x[5] - mu) * rs * g1.y + be1.y;
        o1.z = (x[6] - mu) * rs * g1.z + be1.z;
        o1.w = (x[7] - mu) * rs * g1.w + be1.w;
        float4* op = (float4*)(out + (size_t)n * 128 + s * 8);
        op[0] = o0; op[1] = o1;
    }

    // alpha sweep: alpha[e][h] = ex * inv (scatter, 32B-coalesced)
    if (num > 0) {
        const int h7 = lane & 7, j8 = lane >> 3;   // 8 edges in flight
        float invh = __shfl(inv, 2 * h7);
        for (int i2 = j8; i2 < num; i2 += 8) {
            int pos = start + i2;
            float ex = exbuf[(size_t)pos * 8 + h7];
            int e = eidx[pos];                      // same addr per 8 lanes
            alpha_out[(size_t)e * 8 + h7] = ex * invh;
        }
    }
}

// ============================================================
extern "C" void kernel_launch(void* const* d_in, const int* in_sizes, int n_in,
                              void* d_out, int out_size, void* d_ws, size_t ws_size,
                              hipStream_t stream)
{
    const float* h        = (const float*)d_in[0];
    const int*   edge_idx = (const int*)  d_in[1];
    const float* edge_attr= (const float*)d_in[2];
    const float* w1       = (const float*)d_in[3];
    const float* b1       = (const float*)d_in[4];
    const float* w2       = (const float*)d_in[5];
    const float* b2       = (const float*)d_in[6];
    const float* ln_g     = (const float*)d_in[7];
    const float* ln_b     = (const float*)d_in[8];
    const float* Wl       = (const float*)d_in[9];
    const float* bl       = (const float*)d_in[10];
    const float* Wr       = (const float*)d_in[11];
    const float* br       = (const float*)d_in[12];
    const float* We       = (const float*)d_in[13];
    const float* att      = (const float*)d_in[14];
    const float* bias_out = (const float*)d_in[15];

    float* out   = (float*)d_out;                       // [N,128]
    float* alpha = out + (size_t)N_NODES * 128;         // [E,8] final alpha

    short8* w1p = (short8*)alpha;                       // packed weights live in
    short8* w2p = w1p + 128 * 64;                       // alpha region, consumed by
    short8* Wlp = w2p + 128 * 64;                       // node_ffn; alpha written last
    short8* Wrp = Wlp + 32 * 64;

    float*          v        = (float*)d_ws;                               // [N,128] f32
    unsigned short* xl_bf    = (unsigned short*)(v + (size_t)N_NODES*128); // [N,128] bf16
    unsigned short* xr_bf    = xl_bf + (size_t)N_NODES * 128;              // [N,128] bf16
    float*          exbuf    = (float*)(xr_bf + (size_t)N_NODES * 128);    // [E,8] f32 (ex)
    unsigned*       cnt      = (unsigned*)(exbuf + (size_t)E_EDGES * 8);   // [N]
    int*            rowstart = (int*)(cnt + N_NODES);                      // [N]
    unsigned short* rank     = (unsigned short*)(rowstart + N_NODES);      // [E]
    short8*         Wep      = (short8*)(rank + E_EDGES);                  // [512] 8 KB
    int*            eidx     = (int*)(Wep + 512);                          // [E]
    unsigned*       srcdst   = (unsigned*)(eidx + E_EDGES);                // [E]

    hipMemsetAsync(cnt, 0, (size_t)N_NODES * sizeof(unsigned), stream);

    repack_kernel<<<328, 64, 0, stream>>>(w1, w2, Wl, Wr, We,
                                          w1p, w2p, Wlp, Wrp, Wep);
    count_kernel<<<E_EDGES / 256, 256, 0, stream>>>(edge_idx, cnt, rank);
    node_ffn_mfma<<<N_NODES / 16, 256, 0, stream>>>(
        h, b1, b2, ln_g, ln_b, bl, br, w1p, w2p, Wlp, Wrp, v, xl_bf, xr_bf);
    scan_kernel<<<1, 1024, 0, stream>>>(cnt, rowstart);
    scatter_kernel<<<(E_EDGES + 255) / 256, 256, 0, stream>>>(
        edge_idx, rank, rowstart, eidx, srcdst);
    edge_logits_mfma<<<E_EDGES / 64, 256, 0, stream>>>(
        eidx, srcdst, edge_attr, Wep, att, xl_bf, xr_bf, exbuf);
    node_aggregate_kernel<<<(N_NODES + 3) / 4, 256, 0, stream>>>(
        eidx, rowstart, cnt, srcdst, exbuf, xl_bf, v, bias_out, ln_g, ln_b, alpha, out);
}